// Round 1
// baseline (112.307 us; speedup 1.0000x reference)
//
#include <hip/hip_runtime.h>

// PathEncoder: out[b,x,y,h] = sum_l dot(edata[b, path[b,x,y,l], :], emb[l,h,:]) / clip(dist,1,4)
// Strategy: two passes.
//  Pass 1 (proj_kernel): proj[b,e,j] = dot(edge_feat[b,e,:], W[j,:]), j = l*8+h in [0,32).
//                        Row e==E (pad) written as zeros.
//  Pass 2 (gather_kernel): out[gid,h] = (1/denom) * sum_l proj[b, path_l, l*8+h].

#define E_DIM 4096
#define D_DIM 64
#define L_DIM 4
#define H_DIM 8
#define LH 32                 // L*H
#define B_DIM 16
#define NN 16384              // N*N = 128*128
#define ROWS_PER_B (E_DIM + 1)  // 4097 (includes zero pad row)

// ---------------- Pass 1: per-edge projection ----------------
// One lane per edge row. Row staged in 16 float4 registers; W read at
// wave-uniform addresses (compiler emits s_load through the scalar cache).
__global__ __launch_bounds__(64) void proj_kernel(
    const float* __restrict__ edge_feat,   // [B, E, 64]
    const float* __restrict__ W,           // [32, 64]
    float* __restrict__ proj)              // [B, E+1, 32]
{
    int r = blockIdx.x * 64 + threadIdx.x;          // global row over B*(E+1)
    const int total = B_DIM * ROWS_PER_B;
    if (r >= total) return;
    int b = r / ROWS_PER_B;
    int e = r - b * ROWS_PER_B;

    float* outp = proj + (size_t)r * LH;

    if (e == E_DIM) {                                // zero pad row
        float4 z = make_float4(0.f, 0.f, 0.f, 0.f);
        #pragma unroll
        for (int q = 0; q < 8; ++q) ((float4*)outp)[q] = z;
        return;
    }

    const float4* row4 = (const float4*)(edge_feat + ((size_t)b * E_DIM + e) * D_DIM);
    float4 row[16];
    #pragma unroll
    for (int i = 0; i < 16; ++i) row[i] = row4[i];

    const float4* W4 = (const float4*)W;             // [32][16] float4

    for (int jq = 0; jq < 8; ++jq) {                 // 4 outputs per iter
        float tmp[4];
        #pragma unroll
        for (int jj = 0; jj < 4; ++jj) {
            const int j = jq * 4 + jj;
            float4 acc = make_float4(0.f, 0.f, 0.f, 0.f);
            #pragma unroll
            for (int d4 = 0; d4 < 16; ++d4) {
                float4 w = W4[j * 16 + d4];          // wave-uniform -> s_load
                acc.x += row[d4].x * w.x;
                acc.y += row[d4].y * w.y;
                acc.z += row[d4].z * w.z;
                acc.w += row[d4].w * w.w;
            }
            tmp[jj] = (acc.x + acc.y) + (acc.z + acc.w);
        }
        ((float4*)outp)[jq] = make_float4(tmp[0], tmp[1], tmp[2], tmp[3]);
    }
}

// ---------------- Pass 2: gather + sum + scale ----------------
// One thread per (b,x,y). gid fastest dim = y; h fastest in output.
__global__ __launch_bounds__(256) void gather_kernel(
    const int4* __restrict__ path4,        // [B*N*N] int4 (L=4 packed)
    const int*  __restrict__ dist,         // [B*N*N]
    const float* __restrict__ proj,        // [B, E+1, 32]
    float* __restrict__ out)               // [B*N*N, 8]
{
    int gid = blockIdx.x * 256 + threadIdx.x;        // 262144 threads
    int b = gid >> 14;                               // / (N*N)

    int4 p = path4[gid];
    const float* pb = proj + (size_t)b * ROWS_PER_B * LH;

    // l-th gather reads columns j = l*8 .. l*8+7 of row path_l
    const float4* g0 = (const float4*)(pb + (size_t)p.x * LH + 0);
    const float4* g1 = (const float4*)(pb + (size_t)p.y * LH + 8);
    const float4* g2 = (const float4*)(pb + (size_t)p.z * LH + 16);
    const float4* g3 = (const float4*)(pb + (size_t)p.w * LH + 24);

    float4 a0 = g0[0], a1 = g0[1];
    float4 b0 = g1[0], b1 = g1[1];
    float4 c0 = g2[0], c1 = g2[1];
    float4 d0 = g3[0], d1 = g3[1];

    int dv = dist[gid];
    dv = dv < 1 ? 1 : (dv > L_DIM ? L_DIM : dv);
    float s = 1.0f / (float)dv;                      // exact for 1,2,4; ~1ulp for 3

    float4 o0, o1;
    o0.x = ((a0.x + b0.x) + (c0.x + d0.x)) * s;
    o0.y = ((a0.y + b0.y) + (c0.y + d0.y)) * s;
    o0.z = ((a0.z + b0.z) + (c0.z + d0.z)) * s;
    o0.w = ((a0.w + b0.w) + (c0.w + d0.w)) * s;
    o1.x = ((a1.x + b1.x) + (c1.x + d1.x)) * s;
    o1.y = ((a1.y + b1.y) + (c1.y + d1.y)) * s;
    o1.z = ((a1.z + b1.z) + (c1.z + d1.z)) * s;
    o1.w = ((a1.w + b1.w) + (c1.w + d1.w)) * s;

    float4* op = (float4*)(out + (size_t)gid * 8);
    op[0] = o0;
    op[1] = o1;
}

extern "C" void kernel_launch(void* const* d_in, const int* in_sizes, int n_in,
                              void* d_out, int out_size, void* d_ws, size_t ws_size,
                              hipStream_t stream) {
    const float* edge_feat = (const float*)d_in[0];   // [16,4096,64] f32
    const int*   path      = (const int*)  d_in[1];   // [16,128,128,4] i32
    const int*   dist      = (const int*)  d_in[2];   // [16,128,128] i32
    const float* emb_w     = (const float*)d_in[3];   // [32,64] f32

    float* proj = (float*)d_ws;                       // [16,4097,32] f32 = 8.4 MB

    const int total_rows = B_DIM * ROWS_PER_B;        // 65552
    proj_kernel<<<(total_rows + 63) / 64, 64, 0, stream>>>(edge_feat, emb_w, proj);

    gather_kernel<<<(B_DIM * NN) / 256, 256, 0, stream>>>(
        (const int4*)path, dist, proj, (float*)d_out);
}

// Round 2
// 91.300 us; speedup vs baseline: 1.2301x; 1.2301x over previous
//
#include <hip/hip_runtime.h>

// PathEncoder: out[b,x,y,h] = sum_l dot(edata[b, path[b,x,y,l], :], emb[l,h,:]) / clip(dist,1,4)
// Two passes:
//  Pass 1 (proj_kernel): proj[b,e,j] = dot(edge_feat[b,e,:], W[j,:]), j = l*8+h in [0,32).
//                        Row e==E (pad) written as zeros. W staged in LDS (broadcast reads).
//  Pass 2 (gather_kernel): out[gid,h] = (1/denom) * sum_l proj[b, path_l, l*8+h].
//     XCD-locality: b = blockIdx % 16 pins each graph's 524 KB proj slice to one XCD's L2
//     (consecutive blockIdx round-robin over the 8 XCDs; b and b+8 share an XCD -> ~1 MB/L2).
//     path/dist loads and out stores are non-temporal (streamed once, keep L2 for gathers).

#define E_DIM 4096
#define D_DIM 64
#define L_DIM 4
#define H_DIM 8
#define LH 32                   // L*H
#define B_DIM 16
#define NN 16384                // N*N = 128*128
#define ROWS_PER_B (E_DIM + 1)  // 4097 (includes zero pad row)

typedef float f32x4 __attribute__((ext_vector_type(4)));
typedef int   i32x4 __attribute__((ext_vector_type(4)));

// ---------------- Pass 1: per-edge projection ----------------
__global__ __launch_bounds__(256) void proj_kernel(
    const float* __restrict__ edge_feat,   // [B, E, 64]
    const float* __restrict__ W,           // [32, 64]
    float* __restrict__ proj)              // [B, E+1, 32]
{
    __shared__ f32x4 Wl[LH * 16];          // 32 rows x 16 float4 = 8 KB

    const int tid = threadIdx.x;
    const f32x4* W4 = (const f32x4*)W;     // 512 float4 total
    Wl[tid]       = W4[tid];
    Wl[tid + 256] = W4[tid + 256];
    __syncthreads();

    int r = blockIdx.x * 256 + tid;        // global row over B*(E+1)
    if (r >= B_DIM * ROWS_PER_B) return;
    int b = r / ROWS_PER_B;
    int e = r - b * ROWS_PER_B;

    float* outp = proj + (size_t)r * LH;

    if (e == E_DIM) {                      // zero pad row
        f32x4 z = (f32x4)0.f;
        #pragma unroll
        for (int q = 0; q < 8; ++q) ((f32x4*)outp)[q] = z;
        return;
    }

    const f32x4* row4 = (const f32x4*)(edge_feat + ((size_t)b * E_DIM + e) * D_DIM);
    f32x4 row[16];
    #pragma unroll
    for (int i = 0; i < 16; ++i) row[i] = row4[i];

    for (int jq = 0; jq < 8; ++jq) {       // 4 outputs per iter
        float tmp[4];
        #pragma unroll
        for (int jj = 0; jj < 4; ++jj) {
            const int j = jq * 4 + jj;
            f32x4 acc = (f32x4)0.f;
            #pragma unroll
            for (int d4 = 0; d4 < 16; ++d4) {
                f32x4 w = Wl[j * 16 + d4]; // wave-uniform -> LDS broadcast
                acc += row[d4] * w;
            }
            tmp[jj] = (acc.x + acc.y) + (acc.z + acc.w);
        }
        f32x4 o = { tmp[0], tmp[1], tmp[2], tmp[3] };
        ((f32x4*)outp)[jq] = o;
    }
}

// ---------------- Pass 2: gather + sum + scale ----------------
__global__ __launch_bounds__(256) void gather_kernel(
    const i32x4* __restrict__ path4,       // [B*N*N] int4 (L=4 packed)
    const int*  __restrict__ dist,         // [B*N*N]
    const float* __restrict__ proj,        // [B, E+1, 32]
    float* __restrict__ out)               // [B*N*N, 8]
{
    const int tid   = threadIdx.x;
    const int blk   = blockIdx.x;          // 1024 blocks
    const int b     = blk & 15;            // pin graph b to XCD (b & 7)
    const int chunk = blk >> 4;            // 0..63
    const int gid   = (b << 14) | (chunk << 8) | tid;

    i32x4 p = __builtin_nontemporal_load(path4 + gid);
    int  dv = __builtin_nontemporal_load(dist + gid);

    const float* pb = proj + (size_t)b * ROWS_PER_B * LH;

    // l-th gather reads columns j = l*8 .. l*8+7 of row path_l (L2-resident slice)
    const f32x4* g0 = (const f32x4*)(pb + (size_t)p.x * LH + 0);
    const f32x4* g1 = (const f32x4*)(pb + (size_t)p.y * LH + 8);
    const f32x4* g2 = (const f32x4*)(pb + (size_t)p.z * LH + 16);
    const f32x4* g3 = (const f32x4*)(pb + (size_t)p.w * LH + 24);

    f32x4 a0 = g0[0], a1 = g0[1];
    f32x4 b0 = g1[0], b1 = g1[1];
    f32x4 c0 = g2[0], c1 = g2[1];
    f32x4 d0 = g3[0], d1 = g3[1];

    dv = dv < 1 ? 1 : (dv > L_DIM ? L_DIM : dv);
    float s = 1.0f / (float)dv;            // exact for 1,2,4; ~1ulp for 3

    f32x4 o0 = ((a0 + b0) + (c0 + d0)) * s;
    f32x4 o1 = ((a1 + b1) + (c1 + d1)) * s;

    f32x4* op = (f32x4*)(out + (size_t)gid * 8);
    __builtin_nontemporal_store(o0, op);
    __builtin_nontemporal_store(o1, op + 1);
}

extern "C" void kernel_launch(void* const* d_in, const int* in_sizes, int n_in,
                              void* d_out, int out_size, void* d_ws, size_t ws_size,
                              hipStream_t stream) {
    const float* edge_feat = (const float*)d_in[0];   // [16,4096,64] f32
    const int*   path      = (const int*)  d_in[1];   // [16,128,128,4] i32
    const int*   dist      = (const int*)  d_in[2];   // [16,128,128] i32
    const float* emb_w     = (const float*)d_in[3];   // [32,64] f32

    float* proj = (float*)d_ws;                       // [16,4097,32] f32 = 8.4 MB

    const int total_rows = B_DIM * ROWS_PER_B;        // 65552
    proj_kernel<<<(total_rows + 255) / 256, 256, 0, stream>>>(edge_feat, emb_w, proj);

    gather_kernel<<<(B_DIM * NN) / 256, 256, 0, stream>>>(
        (const i32x4*)path, dist, proj, (float*)d_out);
}

// Round 3
// 83.990 us; speedup vs baseline: 1.3371x; 1.0870x over previous
//
#include <hip/hip_runtime.h>

// PathEncoder: out[b,x,y,h] = sum_l dot(edata[b, path[b,x,y,l], :], emb[l,h,:]) / clip(dist,1,4)
// Two passes, bf16 intermediate table:
//  Pass 1 (proj_kernel): proj[b,e,j] = dot(edge_feat[b,e,:], W[j,:]) computed fp32,
//                        stored bf16 (RNE). Row e==E (pad) = zeros. W staged in LDS.
//  Pass 2 (gather_kernel): out[gid,h] = (1/denom) * sum_l proj_bf16[b, path_l, l*8+h].
//     bf16 table: 16 B gather per path element; per-graph slice 262 KB -> L2-resident.
//     XCD-locality: b = blockIdx % 16 pins graph slices (b, b+8 share an XCD -> 524 KB/L2).

#define E_DIM 4096
#define D_DIM 64
#define L_DIM 4
#define H_DIM 8
#define LH 32                   // L*H
#define B_DIM 16
#define NN 16384                // N*N
#define ROWS_PER_B (E_DIM + 1)  // 4097 (includes zero pad row)

typedef float f32x4 __attribute__((ext_vector_type(4)));
typedef int   i32x4 __attribute__((ext_vector_type(4)));
typedef unsigned int u32;

__device__ __forceinline__ u32 f32_bits(float f) { return __builtin_bit_cast(u32, f); }
__device__ __forceinline__ float bits_f32(u32 u) { return __builtin_bit_cast(float, u); }

// round-to-nearest-even f32 -> bf16 (returned in low 16 bits)
__device__ __forceinline__ u32 f2bf(float f) {
    u32 x = f32_bits(f);
    return (x + 0x7fffu + ((x >> 16) & 1u)) >> 16;
}

// ---------------- Pass 1: per-edge projection (fp32 math, bf16 store) ------
__global__ __launch_bounds__(256) void proj_kernel(
    const float* __restrict__ edge_feat,   // [B, E, 64]
    const float* __restrict__ W,           // [32, 64]
    unsigned short* __restrict__ proj)     // [B, E+1, 32] bf16
{
    __shared__ f32x4 Wl[LH * 16];          // 8 KB

    const int tid = threadIdx.x;
    const f32x4* W4 = (const f32x4*)W;     // 512 float4
    Wl[tid]       = W4[tid];
    Wl[tid + 256] = W4[tid + 256];
    __syncthreads();

    int r = blockIdx.x * 256 + tid;        // row over B*(E+1)
    if (r >= B_DIM * ROWS_PER_B) return;
    int b = r / ROWS_PER_B;
    int e = r - b * ROWS_PER_B;

    i32x4* outp = (i32x4*)(proj + (size_t)r * LH);   // 64 B = 4 x int4

    if (e == E_DIM) {                      // zero pad row
        i32x4 z = (i32x4)0;
        #pragma unroll
        for (int q = 0; q < 4; ++q) outp[q] = z;
        return;
    }

    const f32x4* row4 = (const f32x4*)(edge_feat + ((size_t)b * E_DIM + e) * D_DIM);
    f32x4 row[16];
    #pragma unroll
    for (int i = 0; i < 16; ++i) row[i] = row4[i];

    u32 packed[16];                        // 32 bf16 as 16 u32 pairs
    for (int jq = 0; jq < 8; ++jq) {       // 4 outputs per iter
        float tmp[4];
        #pragma unroll
        for (int jj = 0; jj < 4; ++jj) {
            const int j = jq * 4 + jj;
            f32x4 acc = (f32x4)0.f;
            #pragma unroll
            for (int d4 = 0; d4 < 16; ++d4) {
                acc += row[d4] * Wl[j * 16 + d4];   // uniform -> LDS broadcast
            }
            tmp[jj] = (acc.x + acc.y) + (acc.z + acc.w);
        }
        packed[jq * 2]     = f2bf(tmp[0]) | (f2bf(tmp[1]) << 16);
        packed[jq * 2 + 1] = f2bf(tmp[2]) | (f2bf(tmp[3]) << 16);
    }
    #pragma unroll
    for (int q = 0; q < 4; ++q) {
        i32x4 v = { (int)packed[q*4], (int)packed[q*4+1], (int)packed[q*4+2], (int)packed[q*4+3] };
        outp[q] = v;
    }
}

// ---------------- Pass 2: gather + sum + scale ----------------
__global__ __launch_bounds__(256) void gather_kernel(
    const i32x4* __restrict__ path4,       // [B*N*N] int4 (L=4 packed)
    const int*  __restrict__ dist,         // [B*N*N]
    const unsigned short* __restrict__ proj, // [B, E+1, 32] bf16
    float* __restrict__ out)               // [B*N*N, 8]
{
    const int tid   = threadIdx.x;
    const int blk   = blockIdx.x;          // 1024 blocks
    const int b     = blk & 15;            // pin graph b to an XCD
    const int chunk = blk >> 4;
    const int gid   = (b << 14) | (chunk << 8) | tid;

    i32x4 p = __builtin_nontemporal_load(path4 + gid);
    int  dv = __builtin_nontemporal_load(dist + gid);

    const unsigned short* pb = proj + (size_t)b * ROWS_PER_B * LH;

    // l-th gather: 8 bf16 (16 B) at row path_l, cols l*8..l*8+7 (L2-resident)
    i32x4 A = *(const i32x4*)(pb + (u32)p.x * LH + 0);
    i32x4 Bv= *(const i32x4*)(pb + (u32)p.y * LH + 8);
    i32x4 C = *(const i32x4*)(pb + (u32)p.z * LH + 16);
    i32x4 D = *(const i32x4*)(pb + (u32)p.w * LH + 24);

    dv = dv < 1 ? 1 : (dv > L_DIM ? L_DIM : dv);
    float s = 1.0f / (float)dv;            // exact for 1,2,4; ~1ulp for 3

    f32x4 o0, o1;
    float oo[8];
    #pragma unroll
    for (int k = 0; k < 4; ++k) {
        u32 a = (u32)A[k], bb = (u32)Bv[k], c = (u32)C[k], d = (u32)D[k];
        float fe = (bits_f32(a << 16) + bits_f32(bb << 16))
                 + (bits_f32(c << 16) + bits_f32(d << 16));
        float fo = (bits_f32(a & 0xffff0000u) + bits_f32(bb & 0xffff0000u))
                 + (bits_f32(c & 0xffff0000u) + bits_f32(d & 0xffff0000u));
        oo[2*k]   = fe * s;
        oo[2*k+1] = fo * s;
    }
    o0.x = oo[0]; o0.y = oo[1]; o0.z = oo[2]; o0.w = oo[3];
    o1.x = oo[4]; o1.y = oo[5]; o1.z = oo[6]; o1.w = oo[7];

    f32x4* op = (f32x4*)(out + (size_t)gid * 8);
    __builtin_nontemporal_store(o0, op);
    __builtin_nontemporal_store(o1, op + 1);
}

extern "C" void kernel_launch(void* const* d_in, const int* in_sizes, int n_in,
                              void* d_out, int out_size, void* d_ws, size_t ws_size,
                              hipStream_t stream) {
    const float* edge_feat = (const float*)d_in[0];   // [16,4096,64] f32
    const int*   path      = (const int*)  d_in[1];   // [16,128,128,4] i32
    const int*   dist      = (const int*)  d_in[2];   // [16,128,128] i32
    const float* emb_w     = (const float*)d_in[3];   // [32,64] f32

    unsigned short* proj = (unsigned short*)d_ws;     // [16,4097,32] bf16 = 4.2 MB

    const int total_rows = B_DIM * ROWS_PER_B;        // 65552
    proj_kernel<<<(total_rows + 255) / 256, 256, 0, stream>>>(edge_feat, emb_w, proj);

    gather_kernel<<<(B_DIM * NN) / 256, 256, 0, stream>>>(
        (const i32x4*)path, dist, proj, (float*)d_out);
}